// Round 3
// baseline (2568.683 us; speedup 1.0000x reference)
//
#include <hip/hip_runtime.h>

#define DEV __device__ __forceinline__

typedef _Float16 f16;
typedef _Float16 f16x8 __attribute__((ext_vector_type(8)));
typedef float f32x4 __attribute__((ext_vector_type(4)));

static constexpr int K0P = 416;   // layer0 input dim 400 padded to 13*32
static constexpr int NB  = 16;    // blocks per direction in recurrence
static constexpr int WKP = 424;   // padded K for W LDS rows (53*16B: odd segs -> conflict-free)
static constexpr int NRW = 128;   // padded gate rows per block (112 real: 4 gates * 28)
static constexpr int SMEM_LSTM = NRW*WKP*2 + NRW*33*4 + 800*4; // 128,640 B

// ---------------- math helpers ----------------
DEV float sigf(float x) { return 1.f / (1.f + __expf(-x)); }
DEV float tanhf_(float x) {
  x = fminf(10.f, fmaxf(-10.f, x));
  float e = __expf(2.f * x);
  return (e - 1.f) / (e + 1.f);
}

// ---------------- embedding gather -> x0 f16 [4096][416] ----------------
__global__ void embed_k(const int* __restrict__ wt, const int* __restrict__ pt,
                        const float* __restrict__ we, const float* __restrict__ pe,
                        f16* __restrict__ x0)
{
  const int r = blockIdx.x;
  const int tid = threadIdx.x;
  const int w = wt[r], p = pt[r];
  const float* wrow = we + (size_t)w * 300;
  const float* prow = pe + (size_t)p * 100;
  f16* xr = x0 + (size_t)r * K0P;
  for (int k = tid; k < K0P; k += 128) {
    float v = (k < 300) ? wrow[k] : (k < 400 ? prow[k - 300] : 0.f);
    xr[k] = (f16)v;
  }
}

// ---------------- f32 -> f16 with optional K padding ----------------
__global__ void convpad_k(const float* __restrict__ src, f16* __restrict__ dst,
                          int rows, int K, int KP)
{
  const size_t total = (size_t)rows * KP;
  for (size_t i = (size_t)blockIdx.x * blockDim.x + threadIdx.x; i < total;
       i += (size_t)gridDim.x * blockDim.x) {
    int r = (int)(i / KP), k = (int)(i % KP);
    dst[i] = (f16)(k < K ? src[(size_t)r * K + k] : 0.f);
  }
}

// Whh f32 [2][1600][400] -> reordered f16 [2][NB][NRW][WKP]
__global__ void whh_reorder_k(const float* __restrict__ src, f16* __restrict__ dst)
{
  const int total = 2 * NB * NRW * WKP;
  for (int i = blockIdx.x * blockDim.x + threadIdx.x; i < total;
       i += gridDim.x * blockDim.x) {
    int k = i % WKP, r = (i / WKP) % NRW, blk = (i / (WKP * NRW)) % NB,
        d = i / (WKP * NRW * NB);
    int g = r / 28, uu = r % 28;
    float v = 0.f;
    if (r < 112 && uu < 25 && k < 400)
      v = src[((size_t)d * 1600 + g * 400 + blk * 25 + uu) * 400 + k];
    dst[i] = (f16)v;
  }
}

__global__ void biascat_k(const float* __restrict__ bh, const float* __restrict__ bm,
                          float* __restrict__ bhm)
{
  int i = threadIdx.x;
  bhm[i] = i < 512 ? bh[i] : bm[i - 512];
}

__global__ void zero_k(int* __restrict__ p, int n)
{
  int i = blockIdx.x * blockDim.x + threadIdx.x;
  if (i < n) p[i] = 0;
}

// ---------------- GEMM: C[M][N] = A[M][KP] * B[N][KP]^T + bias[n] ----------------
__global__ __launch_bounds__(256) void gemm_f16_nt(
    const f16* __restrict__ A, const f16* __restrict__ Bw,
    const float* __restrict__ bias, float* __restrict__ C,
    int M, int N, int KP)
{
  __shared__ __align__(16) f16 As[128][40];
  __shared__ __align__(16) f16 Bs[128][40];
  const int tid = threadIdx.x;
  const int bn = blockIdx.x, bm = blockIdx.y;
  const int lane = tid & 63, wid = tid >> 6;
  const int wr = wid >> 1, wc = wid & 1;
  const int srow = tid >> 1, shalf = tid & 1;
  const f16* Ap = A + (size_t)(bm * 128 + srow) * KP + shalf * 16;
  const f16* Bp = Bw + (size_t)(bn * 128 + srow) * KP + shalf * 16;
  const int fr = lane & 15, fq = lane >> 4;
  f32x4 acc[4][4] = {};
  for (int kt = 0; kt < KP; kt += 32) {
    __syncthreads();
    *(uint4*)&As[srow][shalf * 16]     = *(const uint4*)(Ap + kt);
    *(uint4*)&As[srow][shalf * 16 + 8] = *(const uint4*)(Ap + kt + 8);
    *(uint4*)&Bs[srow][shalf * 16]     = *(const uint4*)(Bp + kt);
    *(uint4*)&Bs[srow][shalf * 16 + 8] = *(const uint4*)(Bp + kt + 8);
    __syncthreads();
    f16x8 af[4], bf[4];
    #pragma unroll
    for (int m = 0; m < 4; ++m) af[m] = *(const f16x8*)&As[wr * 64 + m * 16 + fr][fq * 8];
    #pragma unroll
    for (int n = 0; n < 4; ++n) bf[n] = *(const f16x8*)&Bs[wc * 64 + n * 16 + fr][fq * 8];
    #pragma unroll
    for (int m = 0; m < 4; ++m)
      #pragma unroll
      for (int n = 0; n < 4; ++n)
        acc[m][n] = __builtin_amdgcn_mfma_f32_16x16x32_f16(af[m], bf[n], acc[m][n], 0, 0, 0);
  }
  #pragma unroll
  for (int n = 0; n < 4; ++n) {
    const int gn = bn * 128 + wc * 64 + n * 16 + fr;
    const float bv = bias ? bias[gn] : 0.f;
    #pragma unroll
    for (int m = 0; m < 4; ++m) {
      const size_t gm = (size_t)bm * 128 + wr * 64 + m * 16 + fq * 4;
      #pragma unroll
      for (int r = 0; r < 4; ++r)
        C[(gm + r) * (size_t)N + gn] = acc[m][n][r] + bv;
    }
  }
}

// ---------------- recurrence: 32 blocks = 2 dirs x 16 unit-slices ----------------
// flags[2][128][16]: per-producer publish words (zeroed pre-launch)
__global__ __launch_bounds__(256) void lstm_mfma_k(
    const float* __restrict__ gates,
    const f16* __restrict__ whh_r,
    f16* __restrict__ h_out,
    f16* __restrict__ h_glob,
    int* __restrict__ flags)
{
  extern __shared__ char smem[];
  f16*   W_lds = (f16*)smem;                                // [NRW][WKP]
  float* g_lds = (float*)(smem + NRW * WKP * 2);            // [NRW][33]
  float* c_lds = g_lds + NRW * 33;                          // [800]

  const int d = blockIdx.x >> 4, blk = blockIdx.x & 15;
  const int tid = threadIdx.x;
  const int lane = tid & 63, w = tid >> 6;
  const int fr = lane & 15, fq = lane >> 4;
  const int mf0 = w, mf1 = w + 4;

  // W slice -> LDS once
  {
    const uint4* src = (const uint4*)(whh_r + ((size_t)d * NB + blk) * NRW * WKP);
    uint4* dst = (uint4*)W_lds;
    for (int i = tid; i < NRW * WKP / 8; i += 256) dst[i] = src[i];
  }
  for (int i = tid; i < 800; i += 256) c_lds[i] = 0.f;

  // per-thread activation constants (4 (b,uu) pairs per thread)
  const int t0 = d ? 127 : 0;
  const int gdelta = d ? -3200 : 3200;
  const int hodelta = d ? -800 : 800;
  int uuA[4], gr0[4], gr1[4], gr2[4], gr3[4], bA[4];
  bool validA[4];
  const float* gptr[4];
  f16* houtp[4];
  int hoff[4];
  #pragma unroll
  for (int ii = 0; ii < 4; ++ii) {
    const int idx = tid + ii * 256;
    validA[ii] = idx < 800;
    const int b = validA[ii] ? idx / 25 : 0;
    const int uu = validA[ii] ? idx % 25 : 0;
    bA[ii] = b; uuA[ii] = uu;
    gr0[ii] = (uu)      * 33 + b;
    gr1[ii] = (28 + uu) * 33 + b;
    gr2[ii] = (56 + uu) * 33 + b;
    gr3[ii] = (84 + uu) * 33 + b;
    gptr[ii]  = gates + ((size_t)b * 128 + t0) * 3200 + d * 1600 + blk * 25 + uu;
    houtp[ii] = h_out + ((size_t)b * 128 + t0) * 800 + d * 400 + blk * 25 + uu;
    hoff[ii]  = b * 400 + blk * 25 + uu;
  }
  f16* hslab = h_glob + (size_t)d * 128 * 12800;
  int* flagsd = flags + (d << 11);   // d*128*16
  __syncthreads();

  const f16* a0p = W_lds + (size_t)(mf0 * 16 + fr) * WKP + fq * 8;
  const f16* a1p = W_lds + (size_t)(mf1 * 16 + fr) * WKP + fq * 8;

  for (int s = 0; s < 128; ++s) {
    // prefetch this step's gate inputs (latency hides under poll+MFMA)
    float gpre[4][4];
    #pragma unroll
    for (int ii = 0; ii < 4; ++ii)
      if (validA[ii]) {
        gpre[ii][0] = gptr[ii][0];    gpre[ii][1] = gptr[ii][400];
        gpre[ii][2] = gptr[ii][800];  gpre[ii][3] = gptr[ii][1200];
      }

    f32x4 acc00 = {}, acc01 = {}, acc10 = {}, acc11 = {};
    if (s > 0) {
      // wave-parallel poll of the 16 producer flags for step s-1
      int* fl = flagsd + ((s - 1) << 4);
      for (;;) {
        int f = __hip_atomic_load(&fl[lane & 15], __ATOMIC_RELAXED,
                                  __HIP_MEMORY_SCOPE_AGENT);
        if (~__ballot(f != 0) == 0ull) break;
      }
      __builtin_amdgcn_fence(__ATOMIC_ACQUIRE, "agent");
      // B-fragments straight from h_glob (W's zero cols k>=400 nullify over-read)
      const f16* hrow0 = hslab + (size_t)(s - 1) * 12800 + fr * 400 + fq * 8;
      const f16* hrow1 = hrow0 + 16 * 400;
      f16x8 bf0[13], bf1[13];
      #pragma unroll
      for (int kk = 0; kk < 13; ++kk) {
        bf0[kk] = *(const f16x8*)(hrow0 + kk * 32);
        bf1[kk] = *(const f16x8*)(hrow1 + kk * 32);
      }
      #pragma unroll
      for (int kk = 0; kk < 13; ++kk) {
        f16x8 a0 = *(const f16x8*)(a0p + kk * 32);
        f16x8 a1 = *(const f16x8*)(a1p + kk * 32);
        acc00 = __builtin_amdgcn_mfma_f32_16x16x32_f16(a0, bf0[kk], acc00, 0, 0, 0);
        acc01 = __builtin_amdgcn_mfma_f32_16x16x32_f16(a0, bf1[kk], acc01, 0, 0, 0);
        acc10 = __builtin_amdgcn_mfma_f32_16x16x32_f16(a1, bf0[kk], acc10, 0, 0, 0);
        acc11 = __builtin_amdgcn_mfma_f32_16x16x32_f16(a1, bf1[kk], acc11, 0, 0, 0);
      }
    }
    {
      const int row0 = mf0 * 16 + fq * 4, row1 = mf1 * 16 + fq * 4;
      #pragma unroll
      for (int r = 0; r < 4; ++r) {
        g_lds[(row0 + r) * 33 + fr]      = acc00[r];
        g_lds[(row0 + r) * 33 + 16 + fr] = acc01[r];
        g_lds[(row1 + r) * 33 + fr]      = acc10[r];
        g_lds[(row1 + r) * 33 + 16 + fr] = acc11[r];
      }
    }
    __syncthreads();
    f16* hsl = hslab + (size_t)s * 12800;
    #pragma unroll
    for (int ii = 0; ii < 4; ++ii)
      if (validA[ii]) {
        float vi = g_lds[gr0[ii]] + gpre[ii][0];
        float vf = g_lds[gr1[ii]] + gpre[ii][1];
        float vg = g_lds[gr2[ii]] + gpre[ii][2];
        float vo = g_lds[gr3[ii]] + gpre[ii][3];
        const int idx = tid + ii * 256;
        float c = sigf(vf) * c_lds[idx] + sigf(vi) * tanhf_(vg);
        c_lds[idx] = c;
        f16 hf = (f16)(sigf(vo) * tanhf_(c));
        hsl[hoff[ii]] = hf;
        *houtp[ii] = hf;
        gptr[ii] += gdelta;
        houtp[ii] += hodelta;
      }
    __syncthreads();   // drains h stores (vmcnt0) + protects g_lds
    if (tid == 0)
      __hip_atomic_store(&flagsd[(s << 4) + blk], 1, __ATOMIC_RELEASE,
                         __HIP_MEMORY_SCOPE_AGENT);
  }
}

// ---------------- tail ----------------
__global__ __launch_bounds__(256) void tail_k(const float* __restrict__ feat,
                                              const float* __restrict__ wo,
                                              float* __restrict__ s_h,
                                              float* __restrict__ s_m)
{
  const int r = blockIdx.x;
  const int tid = threadIdx.x;
  const float* fr = feat + (size_t)r * 1024;
  float sum = 0.f;
  const int n0 = tid * 4;
  #pragma unroll
  for (int j = 0; j < 4; ++j) sum += tanhf_(fr[n0 + j]) * wo[n0 + j];
  #pragma unroll
  for (int off = 32; off > 0; off >>= 1) sum += __shfl_down(sum, off, 64);
  __shared__ float red[4];
  if ((tid & 63) == 0) red[tid >> 6] = sum;
  __syncthreads();
  if (tid == 0)       s_h[r] = red[0] + red[1];
  else if (tid == 64) s_m[r] = red[2] + red[3];
}

__global__ void score_k(const float* __restrict__ s_h, const float* __restrict__ s_m,
                        const float* __restrict__ bo, float* __restrict__ out)
{
  const int bh = blockIdx.x;
  const int m = threadIdx.x;
  out[(size_t)bh * 128 + m] = s_h[bh] + s_m[(bh & ~127) + m] + bo[0];
}

// ---------------- launch ----------------
extern "C" void kernel_launch(void* const* d_in, const int* in_sizes, int n_in,
                              void* d_out, int out_size, void* d_ws, size_t ws_size,
                              hipStream_t stream)
{
  const int*   wt   = (const int*)d_in[0];
  const int*   pt   = (const int*)d_in[2];
  const float* we   = (const float*)d_in[3];
  const float* pe   = (const float*)d_in[4];
  const float* Wih0 = (const float*)d_in[5];
  const float* Whh0 = (const float*)d_in[6];
  const float* b0   = (const float*)d_in[7];
  const float* Wih1 = (const float*)d_in[8];
  const float* Whh1 = (const float*)d_in[9];
  const float* b1   = (const float*)d_in[10];
  const float* Wh   = (const float*)d_in[11];
  const float* bh   = (const float*)d_in[12];
  const float* Wm   = (const float*)d_in[13];
  const float* bm   = (const float*)d_in[14];
  const float* Wo   = (const float*)d_in[15];
  const float* bo   = (const float*)d_in[16];
  float* out = (float*)d_out;

  char* p = (char*)d_ws;
  auto alloc = [&](size_t bytes) { char* q = p; p += (bytes + 255) & ~(size_t)255; return q; };
  f16*   x0    = (f16*)alloc((size_t)4096 * K0P * 2);
  f16*   wih0  = (f16*)alloc((size_t)3200 * K0P * 2);
  f16*   wih1  = (f16*)alloc((size_t)3200 * 800 * 2);
  f16*   whh0r = (f16*)alloc((size_t)2 * NB * NRW * WKP * 2);
  f16*   whh1r = (f16*)alloc((size_t)2 * NB * NRW * WKP * 2);
  f16*   whm   = (f16*)alloc((size_t)1024 * 800 * 2);
  float* bhm   = (float*)alloc(1024 * 4);
  float* sh    = (float*)alloc(4096 * 4);
  float* sm    = (float*)alloc(4096 * 4);
  f16*   h1    = (f16*)alloc((size_t)4096 * 800 * 2);
  f16*   h2    = (f16*)alloc((size_t)4096 * 800 * 2);
  f16*   hgl   = (f16*)alloc(((size_t)2 * 128 * 32 * 400 + 128) * 2);
  int*   flg   = (int*)alloc((size_t)2 * 2 * 128 * 16 * 4);   // [layer][2][128][16]
  float* gates = (float*)alloc((size_t)4096 * 3200 * 4);
  float* feat  = (float*)gates;

  static bool attr_set = false;
  if (!attr_set) {
    hipFuncSetAttribute((const void*)lstm_mfma_k,
                        hipFuncAttributeMaxDynamicSharedMemorySize, SMEM_LSTM);
    attr_set = true;
  }

  zero_k<<<32, 256, 0, stream>>>(flg, 2 * 2 * 128 * 16);
  embed_k<<<4096, 128, 0, stream>>>(wt, pt, we, pe, x0);
  convpad_k<<<1024, 256, 0, stream>>>(Wih0, wih0, 3200, 400, K0P);
  convpad_k<<<1024, 256, 0, stream>>>(Wih1, wih1, 3200, 800, 800);
  convpad_k<<<1024, 256, 0, stream>>>(Wh, whm, 512, 800, 800);
  convpad_k<<<1024, 256, 0, stream>>>(Wm, whm + (size_t)512 * 800, 512, 800, 800);
  whh_reorder_k<<<1024, 256, 0, stream>>>(Whh0, whh0r);
  whh_reorder_k<<<1024, 256, 0, stream>>>(Whh1, whh1r);
  biascat_k<<<1, 1024, 0, stream>>>(bh, bm, bhm);

  // layer 0
  gemm_f16_nt<<<dim3(25, 32), 256, 0, stream>>>(x0, wih0, b0, gates, 4096, 3200, K0P);
  lstm_mfma_k<<<32, 256, SMEM_LSTM, stream>>>(gates, whh0r, h1, hgl, flg);
  // layer 1
  gemm_f16_nt<<<dim3(25, 32), 256, 0, stream>>>(h1, wih1, b1, gates, 4096, 3200, 800);
  lstm_mfma_k<<<32, 256, SMEM_LSTM, stream>>>(gates, whh1r, h2, hgl, flg + 2 * 128 * 16);
  // features + scorer
  gemm_f16_nt<<<dim3(8, 32), 256, 0, stream>>>(h2, whm, bhm, feat, 4096, 1024, 800);
  tail_k<<<4096, 256, 0, stream>>>(feat, Wo, sh, sm);
  score_k<<<4096, 128, 0, stream>>>(sh, sm, bo, out);
}